// Round 10
// baseline (270.645 us; speedup 1.0000x reference)
//
#include <hip/hip_runtime.h>
#include <math.h>

typedef _Float16 f16;
typedef _Float16 f16x2 __attribute__((ext_vector_type(2)));
typedef _Float16 f16x8 __attribute__((ext_vector_type(8)));
typedef float    f32x16 __attribute__((ext_vector_type(16)));

#define NSEQ 1024
#define CD   128
#define KSTR 136   // Kt row stride f16 (272 B = 17*16 B): 8-lane b128 groups tile all 32 banks
#define VSTR 40    // VtT row stride f16 (80 B = 20 dw): 8-lane b128 groups tile all 32 banks

// Single fused kernel. Block = (bh, qblk): 4 waves x 32 q-rows = 128 q-rows, 512 blocks.
// Per 32-key tile, the block itself transforms raw K/V (R5's pre-kernel work, fused):
//   raw k/v/L -> regs (issued EARLY, latency hidden under MFMA/softmax: T14)
//   -> Lorentz transform in f32 -> LDS:
//   Kt[key][c]   row-major, KSTR=136  -> kf frag = b128 at [lq5*136 + cs*16 + hh*8] (0-conflict)
//   VtT[c][key^rot], VSTR=40, rot=((c>>4)&3)<<3 -> vf frag = b128 (0-conflict read, 2-way write)
// One barrier per tile (dbuf: writes go to buf^1; barrier keeps waves in lockstep-iteration).
// Compute core = R8's verified 32x32 swapped-QK^T + in-lane softmax + 4-shfl P redistribution.
__global__ __launch_bounds__(256)
void ipa_fused(const float* __restrict__ qg, const float* __restrict__ kg,
               const float* __restrict__ vg, const float* __restrict__ Lm,
               float* __restrict__ out)
{
    __shared__ __align__(16) f16 Kt[2][32 * KSTR];   // 17,408 B
    __shared__ __align__(16) f16 Vt[2][128 * VSTR];  // 20,480 B
    const int n = blockIdx.x;                        // 512 blocks = 64 bh x 8 qblk
    const int bh = ((n & 7) << 3) | ((n >> 3) & 7);  // XCD c <- bh octet 8c..8c+7
    const int b  = bh >> 3;
    const int tid = threadIdx.x;
    const int w = tid >> 6, lane = tid & 63;
    const int lq5 = lane & 31, hh = lane >> 5;
    const int qblk = n >> 6;                         // 0..7
    const int q0 = qblk * 128 + w * 32;              // wave owns 32 q-rows
    const float sc2 = 0.12751744154226873f;          // (1/sqrt(128)) * log2(e)

    // staging mapping: thread owns key row krow (0..31) and c-eighth ce (16 floats)
    const int krow = tid >> 3;
    const int ce   = tid & 7;
    const int vrot = (ce & 3) << 3;                  // V key rotation (write-bank spread)
    const float* kgb = kg + ((size_t)bh * NSEQ) * CD + ce * 16;
    const float* vgb = vg + ((size_t)bh * NSEQ) * CD + ce * 16;
    const float* Lmb = Lm + ((size_t)b * NSEQ) * 16;

    float4 kx[4], vx[4], Lx[4];
    auto load_k = [&](int t) {
        const float* p = kgb + (size_t)(t * 32 + krow) * CD;
        #pragma unroll
        for (int j = 0; j < 4; ++j) kx[j] = *(const float4*)(p + j * 4);
    };
    auto load_v = [&](int t) {
        const float* p = vgb + (size_t)(t * 32 + krow) * CD;
        #pragma unroll
        for (int j = 0; j < 4; ++j) vx[j] = *(const float4*)(p + j * 4);
    };
    auto load_L = [&](int t) {
        const float* p = Lmb + (size_t)(t * 32 + krow) * 16;
        #pragma unroll
        for (int j = 0; j < 4; ++j) Lx[j] = *(const float4*)(p + j * 4);
    };
    // K' = (L^T eta) k for vector components (c>=8); scalars pass through
    auto xk_write = [&](int nb) {
        const float* Lv = (const float*)&Lx[0];
        f16 oh[16];
        #pragma unroll
        for (int qd = 0; qd < 4; ++qd) {
            float4 x = kx[qd], y = x;
            int c0 = ce * 16 + qd * 4;
            if (c0 >= 8) {
                float t0 = x.x, t1 = -x.y, t2 = -x.z, t3 = -x.w;
                y.x = Lv[0]*t0 + Lv[4]*t1 + Lv[8] *t2 + Lv[12]*t3;
                y.y = Lv[1]*t0 + Lv[5]*t1 + Lv[9] *t2 + Lv[13]*t3;
                y.z = Lv[2]*t0 + Lv[6]*t1 + Lv[10]*t2 + Lv[14]*t3;
                y.w = Lv[3]*t0 + Lv[7]*t1 + Lv[11]*t2 + Lv[15]*t3;
            }
            oh[qd*4+0] = (f16)y.x; oh[qd*4+1] = (f16)y.y;
            oh[qd*4+2] = (f16)y.z; oh[qd*4+3] = (f16)y.w;
        }
        *(f16x8*)&Kt[nb][krow * KSTR + ce * 16]     = *(f16x8*)&oh[0];
        *(f16x8*)&Kt[nb][krow * KSTR + ce * 16 + 8] = *(f16x8*)&oh[8];
    };
    // V' = (eta L^T eta) v; stored transposed at key index (krow ^ vrot)
    auto xv_write = [&](int nb) {
        const float* Lv = (const float*)&Lx[0];
        f16* vt = &Vt[nb][0];
        const int ki = krow ^ vrot;
        #pragma unroll
        for (int qd = 0; qd < 4; ++qd) {
            float4 x = vx[qd], y = x;
            int c0 = ce * 16 + qd * 4;
            if (c0 >= 8) {
                float t0 = x.x, t1 = -x.y, t2 = -x.z, t3 = -x.w;
                y.x =  (Lv[0]*t0 + Lv[4]*t1 + Lv[8] *t2 + Lv[12]*t3);
                y.y = -(Lv[1]*t0 + Lv[5]*t1 + Lv[9] *t2 + Lv[13]*t3);
                y.z = -(Lv[2]*t0 + Lv[6]*t1 + Lv[10]*t2 + Lv[14]*t3);
                y.w = -(Lv[3]*t0 + Lv[7]*t1 + Lv[11]*t2 + Lv[15]*t3);
            }
            vt[(c0+0)*VSTR + ki] = (f16)y.x;
            vt[(c0+1)*VSTR + ki] = (f16)y.y;
            vt[(c0+2)*VSTR + ki] = (f16)y.z;
            vt[(c0+3)*VSTR + ki] = (f16)y.w;
        }
    };

    // ---- Q: load fp32, transform (M = eta L^T eta), scale, B-frags (R8 verbatim) ----
    f16x8 qf[8];
    {
        int qrow = q0 + lq5;
        const float* Lr = Lm + ((size_t)b * NSEQ + qrow) * 16;
        const float* qp = qg + ((size_t)bh * NSEQ + qrow) * CD;
        float Lv[16];
        #pragma unroll
        for (int i = 0; i < 4; ++i) *(float4*)&Lv[i*4] = *(const float4*)(Lr + i*4);
        #pragma unroll
        for (int cs = 0; cs < 8; ++cs) {
            int c0 = cs * 16 + 8 * hh;
            float4 x0 = *(const float4*)(qp + c0);
            float4 x1 = *(const float4*)(qp + c0 + 4);
            if (c0 >= 8) {
                float t0 = x0.x, t1 = -x0.y, t2 = -x0.z, t3 = -x0.w;
                float4 y;
                y.x =  (Lv[0]*t0 + Lv[4]*t1 + Lv[8] *t2 + Lv[12]*t3);
                y.y = -(Lv[1]*t0 + Lv[5]*t1 + Lv[9] *t2 + Lv[13]*t3);
                y.z = -(Lv[2]*t0 + Lv[6]*t1 + Lv[10]*t2 + Lv[14]*t3);
                y.w = -(Lv[3]*t0 + Lv[7]*t1 + Lv[11]*t2 + Lv[15]*t3);
                x0 = y;
                t0 = x1.x; t1 = -x1.y; t2 = -x1.z; t3 = -x1.w;
                y.x =  (Lv[0]*t0 + Lv[4]*t1 + Lv[8] *t2 + Lv[12]*t3);
                y.y = -(Lv[1]*t0 + Lv[5]*t1 + Lv[9] *t2 + Lv[13]*t3);
                y.z = -(Lv[2]*t0 + Lv[6]*t1 + Lv[10]*t2 + Lv[14]*t3);
                y.w = -(Lv[3]*t0 + Lv[7]*t1 + Lv[11]*t2 + Lv[15]*t3);
                x1 = y;
            }
            qf[cs] = (f16x8){(f16)(x0.x*sc2), (f16)(x0.y*sc2), (f16)(x0.z*sc2), (f16)(x0.w*sc2),
                             (f16)(x1.x*sc2), (f16)(x1.y*sc2), (f16)(x1.z*sc2), (f16)(x1.w*sc2)};
        }
    }

    f32x16 oacc[4];
    #pragma unroll
    for (int cb = 0; cb < 4; ++cb)
        #pragma unroll
        for (int r = 0; r < 16; ++r) oacc[cb][r] = 0.f;
    float mrun = -1e30f, lrun = 0.f;

    // prologue: tile 0 through regs -> LDS buf 0
    load_k(0); load_L(0); load_v(0);
    xk_write(0); xv_write(0);
    __syncthreads();

    for (int t = 0; t < 32; ++t) {                   // 32 keys per tile
        const int cur = t & 1, nxt = cur ^ 1;
        if (t < 31) { load_k(t + 1); load_L(t + 1); }   // hidden under QK^T

        // QK^T: 8 chained MFMA; kf = conflict-free b128 from Kt[cur]
        f32x16 s;
        #pragma unroll
        for (int r = 0; r < 16; ++r) s[r] = 0.f;
        __builtin_amdgcn_s_setprio(1);
        #pragma unroll
        for (int cs = 0; cs < 8; ++cs) {
            f16x8 kf = *(const f16x8*)&Kt[cur][lq5 * KSTR + cs * 16 + hh * 8];
            s = __builtin_amdgcn_mfma_f32_32x32x16_f16(kf, qf[cs], s, 0, 0, 0);
        }
        __builtin_amdgcn_s_setprio(0);

        if (t < 31) { xk_write(nxt); load_v(t + 1); }   // kx freed; vx hidden under softmax/PV

        // in-lane softmax: own 16 keys + partner half via ONE shfl (R8 verbatim)
        float mx = fmaxf(s[0], s[1]);
        #pragma unroll
        for (int r = 2; r < 16; ++r) mx = fmaxf(mx, s[r]);
        mx = fmaxf(mx, __shfl_xor(mx, 32, 64));
        float mnew = fmaxf(mrun, mx);
        if (!__all(mx <= mrun)) {                    // defer-rescale (bit-exact)
            float alpha = exp2f(mrun - mnew);
            lrun *= alpha;
            #pragma unroll
            for (int cb = 0; cb < 4; ++cb) oacc[cb] *= alpha;
            mrun = mnew;
        }
        float pr[16];
        f16 ph[16];
        #pragma unroll
        for (int r = 0; r < 16; ++r) { pr[r] = exp2f(s[r] - mnew); ph[r] = (f16)pr[r]; }
        lrun += ((pr[0]+pr[1])+(pr[2]+pr[3])) + ((pr[4]+pr[5])+(pr[6]+pr[7]))
              + ((pr[8]+pr[9])+(pr[10]+pr[11])) + ((pr[12]+pr[13])+(pr[14]+pr[15]));

        // PA fragments: PA_kh[j] = P[key=16kh+8hh+j]; 2 shfl_xor(32) per kh (R8 verbatim)
        f16x8 pf[2];
        #pragma unroll
        for (int kh = 0; kh < 2; ++kh) {
            union { f16x2 h; unsigned u; } c0{{ph[8*kh+0], ph[8*kh+1]}},
                                           c1{{ph[8*kh+2], ph[8*kh+3]}},
                                           c2{{ph[8*kh+4], ph[8*kh+5]}},
                                           c3{{ph[8*kh+6], ph[8*kh+7]}};
            unsigned wA0 = c0.u, wA1 = c1.u, wB0 = c2.u, wB1 = c3.u;
            unsigned send0 = hh ? wA0 : wB0;
            unsigned send1 = hh ? wA1 : wB1;
            unsigned recv0 = __shfl_xor(send0, 32, 64);
            unsigned recv1 = __shfl_xor(send1, 32, 64);
            union { unsigned u[4]; f16x8 h; } pw;
            pw.u[0] = hh ? recv0 : wA0;
            pw.u[1] = hh ? recv1 : wA1;
            pw.u[2] = hh ? wB0 : recv0;
            pw.u[3] = hh ? wB1 : recv1;
            pf[kh] = pw.h;
        }

        // PV: 8 MFMA (4 independent chains); vf = conflict-free b128 from Vt[cur]
        __builtin_amdgcn_s_setprio(1);
        #pragma unroll
        for (int cb = 0; cb < 4; ++cb) {
            const int c = cb * 32 + lq5;
            const int rc = ((c >> 4) & 3) << 3;      // matches write-side rotation
            #pragma unroll
            for (int kh = 0; kh < 2; ++kh) {
                f16x8 vf = *(const f16x8*)&Vt[cur][c * VSTR + ((kh * 16 + hh * 8) ^ rc)];
                oacc[cb] = __builtin_amdgcn_mfma_f32_32x32x16_f16(vf, pf[kh], oacc[cb], 0, 0, 0);
            }
        }
        __builtin_amdgcn_s_setprio(0);

        if (t < 31) {
            xv_write(nxt);                           // vx -> LDS buf^1
            __syncthreads();                         // tile t+1 fully staged; reads of cur done
        }
    }

    // ---- epilogue: combine halves' l, normalize, final transform (M = L), store ----
    {
        float l = lrun + __shfl_xor(lrun, 32, 64);
        float invl = 1.0f / l;
        int qrow = q0 + lq5;
        const float* Lr = Lm + ((size_t)b * NSEQ + qrow) * 16;
        float Lv[16];
        #pragma unroll
        for (int i = 0; i < 4; ++i) *(float4*)&Lv[i*4] = *(const float4*)(Lr + i*4);
        float* ob = out + ((size_t)bh * NSEQ + qrow) * CD;
        #pragma unroll
        for (int cb = 0; cb < 4; ++cb) {
            #pragma unroll
            for (int rg = 0; rg < 4; ++rg) {
                int c0 = cb * 32 + rg * 8 + 4 * hh;
                float o0 = oacc[cb][rg*4+0] * invl, o1 = oacc[cb][rg*4+1] * invl;
                float o2 = oacc[cb][rg*4+2] * invl, o3 = oacc[cb][rg*4+3] * invl;
                float4 r;
                if (c0 >= 8) {
                    r.x = Lv[0] *o0 + Lv[1] *o1 + Lv[2] *o2 + Lv[3] *o3;
                    r.y = Lv[4] *o0 + Lv[5] *o1 + Lv[6] *o2 + Lv[7] *o3;
                    r.z = Lv[8] *o0 + Lv[9] *o1 + Lv[10]*o2 + Lv[11]*o3;
                    r.w = Lv[12]*o0 + Lv[13]*o1 + Lv[14]*o2 + Lv[15]*o3;
                } else {
                    r.x = o0; r.y = o1; r.z = o2; r.w = o3;
                }
                *(float4*)(ob + c0) = r;
            }
        }
    }
}

extern "C" void kernel_launch(void* const* d_in, const int* in_sizes, int n_in,
                              void* d_out, int out_size, void* d_ws, size_t ws_size,
                              hipStream_t stream) {
    const float* q = (const float*)d_in[0];
    const float* k = (const float*)d_in[1];
    const float* v = (const float*)d_in[2];
    const float* L = (const float*)d_in[3];
    float* o = (float*)d_out;
    ipa_fused<<<512, 256, 0, stream>>>(q, k, v, L, o);
}

// Round 11
// 191.312 us; speedup vs baseline: 1.4147x; 1.4147x over previous
//
#include <hip/hip_runtime.h>
#include <math.h>

typedef _Float16 f16;
typedef _Float16 f16x4 __attribute__((ext_vector_type(4)));
typedef _Float16 f16x8 __attribute__((ext_vector_type(8)));
typedef float    f32x4 __attribute__((ext_vector_type(4)));

typedef const __attribute__((address_space(1))) void gv_t;   // global
typedef __attribute__((address_space(3))) void lv_t;         // LDS

#define NSEQ 1024
#define CD   128
#define LT   136   // pre-kernel LDS f16 row stride (272 B = 17*16 B, keeps b128 alignment)

// khs: [bh][g16 0..63][cs 0..3][lane 0..63][j 0..7]   (131072 f16 per bh)
//   value = Ktr[key = (g16>>1)*32 + 8*(lq>>2) + 4*(g16&1) + (lq&3)][c = cs*32+quad*8+j]
// vhs: [bh][k32 0..31][cb 0..7][lane 0..63][j 0..7]
//   value = Vtr[key = k32*32 + quad*8 + j][c = cb*16 + lq]
// Both are exact MFMA fragment order AND exact linear order for global_load_lds staging.

__global__ __launch_bounds__(256)
void ipa_pre(const float* __restrict__ kg, const float* __restrict__ vg,
             const float* __restrict__ Lm, f16* __restrict__ khs, f16* __restrict__ vhs)
{
    __shared__ float LL[64 * 16];
    __shared__ __align__(16) f16 Kt[64 * LT];
    __shared__ __align__(16) f16 Vt[64 * LT];
    const int bx = blockIdx.x, nt = blockIdx.y, tid = threadIdx.x;
    const int bh = ((bx & 7) << 3) | (bx >> 3);   // XCD x <-> bh 8x..8x+7 (matches attn)
    const int b  = bh >> 3;
    const float* Lb = Lm + ((size_t)b * NSEQ + nt * 64) * 16;
    for (int t = tid; t < 64 * 16; t += 256) LL[t] = Lb[t];
    __syncthreads();

    const size_t base = ((size_t)bh * NSEQ + nt * 64) * CD;
    #pragma unroll
    for (int it = 0; it < 8; ++it) {
        int g = it * 256 + tid;
        int row = g >> 5, cg = g & 31;
        size_t idx = base + row * CD + cg * 4;
        const float* Lr = &LL[row * 16];
        float4 xk = *(const float4*)(kg + idx);
        float4 xv = *(const float4*)(vg + idx);
        float4 yk = xk, yv = xv;
        if (cg >= 2) {
            float t0 = xk.x, t1 = -xk.y, t2 = -xk.z, t3 = -xk.w;   // K: M = L^T eta
            yk.x = Lr[0]*t0 + Lr[4]*t1 + Lr[8] *t2 + Lr[12]*t3;
            yk.y = Lr[1]*t0 + Lr[5]*t1 + Lr[9] *t2 + Lr[13]*t3;
            yk.z = Lr[2]*t0 + Lr[6]*t1 + Lr[10]*t2 + Lr[14]*t3;
            yk.w = Lr[3]*t0 + Lr[7]*t1 + Lr[11]*t2 + Lr[15]*t3;
            t0 = xv.x; t1 = -xv.y; t2 = -xv.z; t3 = -xv.w;         // V: M = eta L^T eta
            yv.x =  (Lr[0]*t0 + Lr[4]*t1 + Lr[8] *t2 + Lr[12]*t3);
            yv.y = -(Lr[1]*t0 + Lr[5]*t1 + Lr[9] *t2 + Lr[13]*t3);
            yv.z = -(Lr[2]*t0 + Lr[6]*t1 + Lr[10]*t2 + Lr[14]*t3);
            yv.w = -(Lr[3]*t0 + Lr[7]*t1 + Lr[11]*t2 + Lr[15]*t3);
        }
        f16x4 hk = {(f16)yk.x, (f16)yk.y, (f16)yk.z, (f16)yk.w};
        f16x4 hv = {(f16)yv.x, (f16)yv.y, (f16)yv.z, (f16)yv.w};
        *(f16x4*)&Kt[row * LT + cg * 4] = hk;
        *(f16x4*)&Vt[row * LT + cg * 4] = hv;
    }
    __syncthreads();

    // staged K out (b128 LDS read -> fully coalesced global store)
    f16* kout = khs + (size_t)bh * 131072 + (size_t)nt * 4 * 4 * 512;
    #pragma unroll
    for (int it = 0; it < 4; ++it) {
        int slot = it * 256 + tid;                 // (g16l, cs, L)
        int g16l = slot >> 8, cs = (slot >> 6) & 3, L = slot & 63;
        int lq = L & 15, quad = L >> 4;
        int keyl = ((g16l >> 1) << 5) + ((lq >> 2) << 3) + ((g16l & 1) << 2) + (lq & 3);
        f16x8 kv = *(const f16x8*)&Kt[keyl * LT + cs * 32 + quad * 8];
        *(f16x8*)(kout + (g16l * 4 + cs) * 512 + L * 8) = kv;
    }
    // staged V^T out (scalar LDS column reads -> coalesced global store)
    f16* vout = vhs + (size_t)bh * 131072 + (size_t)nt * 2 * 8 * 512;
    #pragma unroll
    for (int it = 0; it < 4; ++it) {
        int slot = it * 256 + tid;                 // (k32l, cb, L)
        int k32l = slot >> 9, cb = (slot >> 6) & 7, L = slot & 63;
        int lq = L & 15, quad = L >> 4;
        int c = cb * 16 + lq;
        f16x8 o;
        #pragma unroll
        for (int j = 0; j < 8; ++j)
            o[j] = Vt[(k32l * 32 + quad * 8 + j) * LT + c];
        *(f16x8*)(vout + (k32l * 8 + cb) * 512 + L * 8) = o;
    }
}

// ---------------- attention: LDS-shared K/V, 4 waves/block, 2-phase dbuf ----------------
// All 4 waves consume the SAME K/V tile (fragments are q-independent): global traffic /4.
// Staging uses global_load_lds (layout is already linear fragment order), double-buffered,
// one barrier per K-tile. Empirical best total across the R0-R10 structural matrix.
__global__ __launch_bounds__(256, 2)
void ipa_attn(const float* __restrict__ qg, const f16* __restrict__ khs,
              const f16* __restrict__ vhs, const float* __restrict__ Lm,
              float* __restrict__ out)
{
    __shared__ __align__(16) f16 sK[2][8192];   // 16 KB per buffer
    __shared__ __align__(16) f16 sV[2][8192];   // 16 KB per buffer
    const int n = blockIdx.x;                   // 512 blocks = 64 bh x 8 qblk
    const int bh = ((n & 7) << 3) | ((n >> 3) & 7);   // XCD-local bh group (matches pre)
    const int b  = bh >> 3;
    const int tid = threadIdx.x;
    const int w = tid >> 6, lane = tid & 63, lq = lane & 15, quad = lane >> 4;
    const int qblk = n >> 6;                    // 0..7
    const int q0 = qblk * 128 + w * 32;         // wave owns 32 q-rows
    const f16* kbh = khs + (size_t)bh * 131072;
    const f16* vbh = vhs + (size_t)bh * 131072;
    const float sc2 = 0.12751744154226873f;     // (1/sqrt(128)) * log2(e)

    // issue one K/V tile (16 KB + 16 KB) into LDS buffer nb; 8 x 1KB gl_lds per wave
    auto stage = [&](int nb, int it) {
        const char* kp = (const char*)(kbh + (size_t)it * 8192);
        const char* vp = (const char*)(vbh + (size_t)it * 8192);
        char* kd = (char*)&sK[nb][0];
        char* vd = (char*)&sV[nb][0];
        #pragma unroll
        for (int j = 0; j < 4; ++j) {
            int off = (w * 4 + j) * 1024;       // wave-uniform LDS dest; per-lane global src
            __builtin_amdgcn_global_load_lds((gv_t*)(kp + off + lane * 16),
                                             (lv_t*)(kd + off), 16, 0, 0);
            __builtin_amdgcn_global_load_lds((gv_t*)(vp + off + lane * 16),
                                             (lv_t*)(vd + off), 16, 0, 0);
        }
    };

    // ---- Q: load fp32, transform (M = eta L^T eta) per-lane, scale, make frags ----
    f16x8 qf[2][4];
    #pragma unroll
    for (int u = 0; u < 2; ++u) {
        int qrow = q0 + u * 16 + lq;
        const float* Lr = Lm + ((size_t)b * NSEQ + qrow) * 16;
        const float* qp = qg + ((size_t)bh * NSEQ + qrow) * CD;
        float Lv[16];
        #pragma unroll
        for (int i = 0; i < 4; ++i) *(float4*)&Lv[i*4] = *(const float4*)(Lr + i*4);
        #pragma unroll
        for (int cs = 0; cs < 4; ++cs) {
            int c0 = cs * 32 + quad * 8;
            float4 x0 = *(const float4*)(qp + c0);
            float4 x1 = *(const float4*)(qp + c0 + 4);
            if (c0 >= 8) {
                float t0 = x0.x, t1 = -x0.y, t2 = -x0.z, t3 = -x0.w;
                float4 y;
                y.x =  (Lv[0]*t0 + Lv[4]*t1 + Lv[8] *t2 + Lv[12]*t3);
                y.y = -(Lv[1]*t0 + Lv[5]*t1 + Lv[9] *t2 + Lv[13]*t3);
                y.z = -(Lv[2]*t0 + Lv[6]*t1 + Lv[10]*t2 + Lv[14]*t3);
                y.w = -(Lv[3]*t0 + Lv[7]*t1 + Lv[11]*t2 + Lv[15]*t3);
                x0 = y;
                t0 = x1.x; t1 = -x1.y; t2 = -x1.z; t3 = -x1.w;
                y.x =  (Lv[0]*t0 + Lv[4]*t1 + Lv[8] *t2 + Lv[12]*t3);
                y.y = -(Lv[1]*t0 + Lv[5]*t1 + Lv[9] *t2 + Lv[13]*t3);
                y.z = -(Lv[2]*t0 + Lv[6]*t1 + Lv[10]*t2 + Lv[14]*t3);
                y.w = -(Lv[3]*t0 + Lv[7]*t1 + Lv[11]*t2 + Lv[15]*t3);
                x1 = y;
            }
            qf[u][cs] = (f16x8){(f16)(x0.x*sc2), (f16)(x0.y*sc2), (f16)(x0.z*sc2), (f16)(x0.w*sc2),
                                (f16)(x1.x*sc2), (f16)(x1.y*sc2), (f16)(x1.z*sc2), (f16)(x1.w*sc2)};
        }
    }

    f32x4 oacc[2][8];
    #pragma unroll
    for (int u = 0; u < 2; ++u)
        #pragma unroll
        for (int cb = 0; cb < 8; ++cb) oacc[u][cb] = (f32x4){0.f, 0.f, 0.f, 0.f};
    float mrun[2] = {-1e30f, -1e30f}, lrun[2] = {0.f, 0.f};

    stage(0, 0);

    for (int it = 0; it < 16; ++it) {                 // 64 keys per iteration
        const int cur = it & 1;
        __syncthreads();                              // stage(cur) complete; prev reads done
        if (it < 15) stage(cur ^ 1, it + 1);          // overlap next-tile loads with compute

        const f16* kb = &sK[cur][0];
        const f16* vb = &sV[cur][0];
        f16x8 kf[4][4];
        #pragma unroll
        for (int g = 0; g < 4; ++g)
            #pragma unroll
            for (int cs = 0; cs < 4; ++cs)
                kf[g][cs] = *(const f16x8*)&kb[(g * 4 + cs) * 512 + lane * 8];

        f32x4 s[2][4];
        #pragma unroll
        for (int u = 0; u < 2; ++u)
            #pragma unroll
            for (int g = 0; g < 4; ++g) s[u][g] = (f32x4){0.f, 0.f, 0.f, 0.f};
        #pragma unroll
        for (int g = 0; g < 4; ++g)
            #pragma unroll
            for (int cs = 0; cs < 4; ++cs) {
                s[0][g] = __builtin_amdgcn_mfma_f32_16x16x32_f16(kf[g][cs], qf[0][cs], s[0][g], 0, 0, 0);
                s[1][g] = __builtin_amdgcn_mfma_f32_16x16x32_f16(kf[g][cs], qf[1][cs], s[1][g], 0, 0, 0);
            }

        f16x8 vf[2][8];
        #pragma unroll
        for (int k2 = 0; k2 < 2; ++k2)
            #pragma unroll
            for (int cb = 0; cb < 8; ++cb)
                vf[k2][cb] = *(const f16x8*)&vb[(k2 * 8 + cb) * 512 + lane * 8];

        // exp2-domain online softmax (scores already scaled by log2e)
        f16x8 pf[2][2];
        #pragma unroll
        for (int u = 0; u < 2; ++u) {
            float mx = -1e30f;
            #pragma unroll
            for (int g = 0; g < 4; ++g)
                mx = fmaxf(mx, fmaxf(fmaxf(s[u][g].x, s[u][g].y), fmaxf(s[u][g].z, s[u][g].w)));
            mx = fmaxf(mx, __shfl_xor(mx, 16, 64));
            mx = fmaxf(mx, __shfl_xor(mx, 32, 64));
            float mnew = fmaxf(mrun[u], mx);
            // defer-rescale (bit-exact): when no lane sees a new max, alpha==1 exactly
            if (!__all(mx <= mrun[u])) {
                float alpha = exp2f(mrun[u] - mnew);
                lrun[u] *= alpha;
                #pragma unroll
                for (int cb = 0; cb < 8; ++cb) oacc[u][cb] *= alpha;
                mrun[u] = mnew;
            }
            float p[16], rs = 0.f;
            #pragma unroll
            for (int g = 0; g < 4; ++g) {
                p[g*4+0] = exp2f(s[u][g].x - mnew);
                p[g*4+1] = exp2f(s[u][g].y - mnew);
                p[g*4+2] = exp2f(s[u][g].z - mnew);
                p[g*4+3] = exp2f(s[u][g].w - mnew);
                rs += (p[g*4+0] + p[g*4+1]) + (p[g*4+2] + p[g*4+3]);
            }
            rs += __shfl_xor(rs, 16, 64);
            rs += __shfl_xor(rs, 32, 64);
            lrun[u] += rs;
            pf[u][0] = (f16x8){(f16)p[0],(f16)p[1],(f16)p[2],(f16)p[3],(f16)p[4],(f16)p[5],(f16)p[6],(f16)p[7]};
            pf[u][1] = (f16x8){(f16)p[8],(f16)p[9],(f16)p[10],(f16)p[11],(f16)p[12],(f16)p[13],(f16)p[14],(f16)p[15]};
        }
        #pragma unroll
        for (int k2 = 0; k2 < 2; ++k2)
            #pragma unroll
            for (int cb = 0; cb < 8; ++cb) {
                oacc[0][cb] = __builtin_amdgcn_mfma_f32_16x16x32_f16(vf[k2][cb], pf[0][k2], oacc[0][cb], 0, 0, 0);
                oacc[1][cb] = __builtin_amdgcn_mfma_f32_16x16x32_f16(vf[k2][cb], pf[1][k2], oacc[1][cb], 0, 0, 0);
            }
    }

    // ---- epilogue: normalize, final frame transform (M = L), store ----
    #pragma unroll
    for (int u = 0; u < 2; ++u) {
        int qrow = q0 + u * 16 + lq;
        float invl = 1.0f / lrun[u];
        const float* Lr = Lm + ((size_t)b * NSEQ + qrow) * 16;
        float* ob = out + ((size_t)bh * NSEQ + qrow) * CD;
        #pragma unroll
        for (int cb = 0; cb < 8; ++cb) {
            int c0 = cb * 16 + quad * 4;
            float o0 = oacc[u][cb].x*invl, o1 = oacc[u][cb].y*invl;
            float o2 = oacc[u][cb].z*invl, o3 = oacc[u][cb].w*invl;
            float4 r;
            if (c0 >= 8) {
                r.x = Lr[0] *o0 + Lr[1] *o1 + Lr[2] *o2 + Lr[3] *o3;
                r.y = Lr[4] *o0 + Lr[5] *o1 + Lr[6] *o2 + Lr[7] *o3;
                r.z = Lr[8] *o0 + Lr[9] *o1 + Lr[10]*o2 + Lr[11]*o3;
                r.w = Lr[12]*o0 + Lr[13]*o1 + Lr[14]*o2 + Lr[15]*o3;
            } else {
                r.x = o0; r.y = o1; r.z = o2; r.w = o3;
            }
            *(float4*)(ob + c0) = r;
        }
    }
}

extern "C" void kernel_launch(void* const* d_in, const int* in_sizes, int n_in,
                              void* d_out, int out_size, void* d_ws, size_t ws_size,
                              hipStream_t stream) {
    const float* q = (const float*)d_in[0];
    const float* k = (const float*)d_in[1];
    const float* v = (const float*)d_in[2];
    const float* L = (const float*)d_in[3];
    float* o = (float*)d_out;
    f16* khs = (f16*)d_ws;                       // 16.78 MB
    f16* vhs = khs + (size_t)64 * 131072;        // 16.78 MB
    dim3 grid1(64, 16);
    ipa_pre<<<grid1, 256, 0, stream>>>(k, v, L, khs, vhs);
    ipa_attn<<<512, 256, 0, stream>>>(q, khs, vhs, L, o);
}